// Round 9
// baseline (205.195 us; speedup 1.0000x reference)
//
#include <hip/hip_runtime.h>
#include <hip/hip_bf16.h>
#include <hip/hip_cooperative_groups.h>

namespace cg = cooperative_groups;

#define Bsz 16
#define Nn  1024
#define Ff  256
#define ALPHA 0.2f
#define NEG_BIG -9.0e15f

typedef __attribute__((ext_vector_type(8))) short short8;
typedef __attribute__((ext_vector_type(4))) float f32x4;
typedef __attribute__((ext_vector_type(4))) unsigned short ushort4_t;

__device__ __forceinline__ unsigned short f2bf(float x) {
    union { __hip_bfloat16 b; unsigned short u; } cv;
    cv.b = __float2bfloat16(x);
    return cv.u;
}

// ---- fallback K0: blocks 0..63: w1/w2 ; blocks 64..71: pack WK ------------
__global__ __launch_bounds__(256) void gat_prep(
    const float* __restrict__ W, const float* __restrict__ a,
    float* __restrict__ w1, float* __restrict__ w2,
    unsigned short* __restrict__ WK)
{
    const int t = threadIdx.x, w = t >> 6, ln = t & 63;
    if (blockIdx.x < 64) {
        __shared__ float a1s[Ff], a2s[Ff];
        a1s[t] = a[t];
        a2s[t] = a[Ff + t];
        __syncthreads();
        const int f = blockIdx.x * 4 + w;
        float s1 = 0.f, s2 = 0.f;
        #pragma unroll
        for (int c = 0; c < 4; c++) {
            const int o = ln + 64 * c;
            const float wv = W[(size_t)f * Ff + o];
            s1 += wv * a1s[o];
            s2 += wv * a2s[o];
        }
        #pragma unroll
        for (int off = 1; off < 64; off <<= 1) {
            s1 += __shfl_xor(s1, off, 64);
            s2 += __shfl_xor(s2, off, 64);
        }
        if (ln == 0) { w1[f] = s1; w2[f] = s2; }
        return;
    }
    __shared__ __align__(16) float tile[32][258];
    const int ft = blockIdx.x - 64;
    const float* src = W + (size_t)ft * 32 * Ff;
    #pragma unroll
    for (int rr = 0; rr < 8; rr++) {
        const int row = rr * 4 + w;
        const int col = ln * 4;
        const float4 v = *(const float4*)&src[row * Ff + col];
        float2* tr = (float2*)&tile[row][col];
        tr[0] = make_float2(v.x, v.y);
        tr[1] = make_float2(v.z, v.w);
    }
    __syncthreads();
    unsigned* d32 = (unsigned*)(WK + (size_t)ft * 8192);
    #pragma unroll
    for (int k = 0; k < 16; k++) {
        const int fidx = k * 256 + t;
        const int o = fidx >> 4, q = fidx & 15;
        const unsigned lo = f2bf(tile[2 * q][o]);
        const unsigned hi = f2bf(tile[2 * q + 1][o]);
        d32[fidx] = lo | (hi << 16);
    }
}

// ---- fallback K1: stage h-tile -> f1/f2 + Wh = h@W (MFMA) -> WhK ----------
__global__ __launch_bounds__(256) void pack_f(
    const float* __restrict__ h, const unsigned short* __restrict__ WK,
    const float* __restrict__ w1, const float* __restrict__ w2,
    unsigned short* __restrict__ WhK,
    float* __restrict__ f1, float* __restrict__ f2)
{
    __shared__ __align__(16) float tile[32][258];
    const int id = blockIdx.x, t = threadIdx.x, w = t >> 6, ln = t & 63;
    const int grow0 = id * 32;
    const float* src = h + (size_t)grow0 * Ff;
    #pragma unroll
    for (int rr = 0; rr < 8; rr++) {
        const int row = rr * 4 + w;
        const int col = ln * 4;
        const float4 v = *(const float4*)&src[row * Ff + col];
        float2* tr = (float2*)&tile[row][col];
        tr[0] = make_float2(v.x, v.y);
        tr[1] = make_float2(v.z, v.w);
    }
    __syncthreads();

    {
        float w1r[4], w2r[4];
        #pragma unroll
        for (int c = 0; c < 4; c++) {
            w1r[c] = w1[ln + 64 * c];
            w2r[c] = w2[ln + 64 * c];
        }
        #pragma unroll
        for (int rr = 0; rr < 8; rr++) {
            const int row = rr * 4 + w;
            float s1 = 0.f, s2 = 0.f;
            #pragma unroll
            for (int c = 0; c < 4; c++) {
                const float hv = tile[row][ln + 64 * c];
                s1 += hv * w1r[c];
                s2 += hv * w2r[c];
            }
            #pragma unroll
            for (int off = 1; off < 64; off <<= 1) {
                s1 += __shfl_xor(s1, off, 64);
                s2 += __shfl_xor(s2, off, 64);
            }
            if (ln == 0) { f1[grow0 + row] = s1; f2[grow0 + row] = s2; }
        }
    }

    const int m = ln & 15, quad = ln >> 4;
    f32x4 acc0[4], acc1[4];
    #pragma unroll
    for (int nt = 0; nt < 4; nt++) {
        f32x4 z = {0.f, 0.f, 0.f, 0.f};
        acc0[nt] = z; acc1[nt] = z;
    }
    #pragma unroll
    for (int kt = 0; kt < 8; kt++) {
        short8 a0, a1;
        {
            const float* p0 = &tile[m][kt * 32 + quad * 8];
            const float* p1 = &tile[16 + m][kt * 32 + quad * 8];
            #pragma unroll
            for (int e = 0; e < 8; e++) {
                a0[e] = (short)f2bf(p0[e]);
                a1[e] = (short)f2bf(p1[e]);
            }
        }
        #pragma unroll
        for (int nt = 0; nt < 4; nt++) {
            const short8 bfr = *(const short8*)&WK[(size_t)kt * 8192 + (w * 64 + nt * 16 + m) * 32 + quad * 8];
            acc0[nt] = __builtin_amdgcn_mfma_f32_16x16x32_bf16(a0, bfr, acc0[nt], 0, 0, 0);
            acc1[nt] = __builtin_amdgcn_mfma_f32_16x16x32_bf16(a1, bfr, acc1[nt], 0, 0, 0);
        }
    }
    unsigned short* dst = WhK + (size_t)id * 8192;
    #pragma unroll
    for (int nt = 0; nt < 4; nt++) {
        const int o = w * 64 + nt * 16 + m;
        ushort4_t v0 = { f2bf(acc0[nt][0]), f2bf(acc0[nt][1]),
                         f2bf(acc0[nt][2]), f2bf(acc0[nt][3]) };
        ushort4_t v1 = { f2bf(acc1[nt][0]), f2bf(acc1[nt][1]),
                         f2bf(acc1[nt][2]), f2bf(acc1[nt][3]) };
        *(ushort4_t*)&dst[o * 32 + quad * 4]      = v0;
        *(ushort4_t*)&dst[o * 32 + 16 + quad * 4] = v1;
    }
}

// ---- K_pre: cooperative merge of gat_prep + pack_f (S0 -> grid.sync -> S1).
// 512 blocks x 256 thr, 35 KB LDS -> 4 blocks/CU co-residency capacity = 1024
// >= 512 (2x margin; r5's coop failure was a zero-margin 512x1024 launch).
__global__ __launch_bounds__(256) void k_pre(
    const float* __restrict__ h, const float* __restrict__ W,
    const float* __restrict__ a,
    unsigned short* __restrict__ WK,
    float* __restrict__ w1, float* __restrict__ w2,
    unsigned short* __restrict__ WhK,
    float* __restrict__ f1, float* __restrict__ f2)
{
    __shared__ __align__(16) float tile[32][258];
    __shared__ float a1s[Ff], a2s[Ff];
    const int bid = blockIdx.x, t = threadIdx.x, w = t >> 6, ln = t & 63;

    // ---- S0 ----
    if (bid < 64) {
        a1s[t] = a[t];
        a2s[t] = a[Ff + t];
        __syncthreads();
        const int f = bid * 4 + w;
        float s1 = 0.f, s2 = 0.f;
        #pragma unroll
        for (int c = 0; c < 4; c++) {
            const int o = ln + 64 * c;
            const float wv = W[(size_t)f * Ff + o];
            s1 += wv * a1s[o];
            s2 += wv * a2s[o];
        }
        #pragma unroll
        for (int off = 1; off < 64; off <<= 1) {
            s1 += __shfl_xor(s1, off, 64);
            s2 += __shfl_xor(s2, off, 64);
        }
        if (ln == 0) { w1[f] = s1; w2[f] = s2; }
    } else if (bid < 72) {
        const int ft = bid - 64;
        const float* src = W + (size_t)ft * 32 * Ff;
        #pragma unroll
        for (int rr = 0; rr < 8; rr++) {
            const int row = rr * 4 + w;
            const int col = ln * 4;
            const float4 v = *(const float4*)&src[row * Ff + col];
            float2* tr = (float2*)&tile[row][col];
            tr[0] = make_float2(v.x, v.y);
            tr[1] = make_float2(v.z, v.w);
        }
        __syncthreads();
        unsigned* d32 = (unsigned*)(WK + (size_t)ft * 8192);
        #pragma unroll
        for (int k = 0; k < 16; k++) {
            const int fidx = k * 256 + t;
            const int o = fidx >> 4, q = fidx & 15;
            const unsigned lo = f2bf(tile[2 * q][o]);
            const unsigned hi = f2bf(tile[2 * q + 1][o]);
            d32[fidx] = lo | (hi << 16);
        }
    }

    cg::this_grid().sync();

    // ---- S1: pack_f body (r8-verbatim) ----
    const int grow0 = bid * 32;
    const float* src = h + (size_t)grow0 * Ff;
    #pragma unroll
    for (int rr = 0; rr < 8; rr++) {
        const int row = rr * 4 + w;
        const int col = ln * 4;
        const float4 v = *(const float4*)&src[row * Ff + col];
        float2* tr = (float2*)&tile[row][col];
        tr[0] = make_float2(v.x, v.y);
        tr[1] = make_float2(v.z, v.w);
    }
    __syncthreads();

    {
        float w1r[4], w2r[4];
        #pragma unroll
        for (int c = 0; c < 4; c++) {
            w1r[c] = w1[ln + 64 * c];
            w2r[c] = w2[ln + 64 * c];
        }
        #pragma unroll
        for (int rr = 0; rr < 8; rr++) {
            const int row = rr * 4 + w;
            float s1 = 0.f, s2 = 0.f;
            #pragma unroll
            for (int c = 0; c < 4; c++) {
                const float hv = tile[row][ln + 64 * c];
                s1 += hv * w1r[c];
                s2 += hv * w2r[c];
            }
            #pragma unroll
            for (int off = 1; off < 64; off <<= 1) {
                s1 += __shfl_xor(s1, off, 64);
                s2 += __shfl_xor(s2, off, 64);
            }
            if (ln == 0) { f1[grow0 + row] = s1; f2[grow0 + row] = s2; }
        }
    }

    const int m = ln & 15, quad = ln >> 4;
    f32x4 acc0[4], acc1[4];
    #pragma unroll
    for (int nt = 0; nt < 4; nt++) {
        f32x4 z = {0.f, 0.f, 0.f, 0.f};
        acc0[nt] = z; acc1[nt] = z;
    }
    #pragma unroll
    for (int kt = 0; kt < 8; kt++) {
        short8 a0, a1;
        {
            const float* p0 = &tile[m][kt * 32 + quad * 8];
            const float* p1 = &tile[16 + m][kt * 32 + quad * 8];
            #pragma unroll
            for (int e = 0; e < 8; e++) {
                a0[e] = (short)f2bf(p0[e]);
                a1[e] = (short)f2bf(p1[e]);
            }
        }
        #pragma unroll
        for (int nt = 0; nt < 4; nt++) {
            const short8 bfr = *(const short8*)&WK[(size_t)kt * 8192 + (w * 64 + nt * 16 + m) * 32 + quad * 8];
            acc0[nt] = __builtin_amdgcn_mfma_f32_16x16x32_bf16(a0, bfr, acc0[nt], 0, 0, 0);
            acc1[nt] = __builtin_amdgcn_mfma_f32_16x16x32_bf16(a1, bfr, acc1[nt], 0, 0, 0);
        }
    }
    unsigned short* dst = WhK + (size_t)bid * 8192;
    #pragma unroll
    for (int nt = 0; nt < 4; nt++) {
        const int o = w * 64 + nt * 16 + m;
        ushort4_t v0 = { f2bf(acc0[nt][0]), f2bf(acc0[nt][1]),
                         f2bf(acc0[nt][2]), f2bf(acc0[nt][3]) };
        ushort4_t v1 = { f2bf(acc1[nt][0]), f2bf(acc1[nt][1]),
                         f2bf(acc1[nt][2]), f2bf(acc1[nt][3]) };
        *(ushort4_t*)&dst[o * 32 + quad * 4]      = v0;
        *(ushort4_t*)&dst[o * 32 + 16 + quad * 4] = v1;
    }
}

// ---- K2: softmax -> out = elu( P @ Wh ) (r8-verbatim, 40.9 us proven) -----
#define TI 32
#define PST 1040
__global__ __launch_bounds__(1024, 8) void gat_attn(
    const int* __restrict__ adj,
    const float* __restrict__ f1, const float* __restrict__ f2,
    const unsigned short* __restrict__ WhK,
    float* __restrict__ out)
{
    __shared__ __align__(16) unsigned short pbf[TI * PST];   // 66,560 B
    const int t = threadIdx.x, w = t >> 6, ln = t & 63;      // 16 waves
    const int m = ln & 15, quad = ln >> 4;
    const int bid = blockIdx.x;
    const int b  = 2 * (bid & 7) + ((bid >> 3) & 1);         // XCD-local batches
    const int i0 = (bid >> 4) * TI;

    const int r0 = 2 * w, r1 = r0 + 1;
    const int grb = b * Nn + i0 + r0;
    const int* aptr = adj + (size_t)grb * Nn;
    int4 av0[4], av1[4];
    #pragma unroll
    for (int c = 0; c < 4; c++) {
        av0[c] = *(const int4*)&aptr[c * 256 + 4 * ln];
        av1[c] = *(const int4*)&aptr[Nn + c * 256 + 4 * ln];
    }
    float4 f2r[4];
    #pragma unroll
    for (int c = 0; c < 4; c++)
        f2r[c] = *(const float4*)&f2[b * Nn + 256 * c + 4 * ln];

    const float fi0 = f1[grb], fi1 = f1[grb + 1];
    float e0[16], e1[16];
    float mx0 = -INFINITY, mx1 = -INFINITY;
    #pragma unroll
    for (int c = 0; c < 4; c++) {
        const float4 fv = f2r[c];
        float x, y;
        x = fi0 + fv.x; x = fmaxf(x, ALPHA * x); x = av0[c].x > 0 ? x : NEG_BIG; e0[4*c+0] = x;
        y = fi0 + fv.y; y = fmaxf(y, ALPHA * y); y = av0[c].y > 0 ? y : NEG_BIG; e0[4*c+1] = y;
        mx0 = fmaxf(fmaxf(x, y), mx0);
        x = fi0 + fv.z; x = fmaxf(x, ALPHA * x); x = av0[c].z > 0 ? x : NEG_BIG; e0[4*c+2] = x;
        y = fi0 + fv.w; y = fmaxf(y, ALPHA * y); y = av0[c].w > 0 ? y : NEG_BIG; e0[4*c+3] = y;
        mx0 = fmaxf(fmaxf(x, y), mx0);
        x = fi1 + fv.x; x = fmaxf(x, ALPHA * x); x = av1[c].x > 0 ? x : NEG_BIG; e1[4*c+0] = x;
        y = fi1 + fv.y; y = fmaxf(y, ALPHA * y); y = av1[c].y > 0 ? y : NEG_BIG; e1[4*c+1] = y;
        mx1 = fmaxf(fmaxf(x, y), mx1);
        x = fi1 + fv.z; x = fmaxf(x, ALPHA * x); x = av1[c].z > 0 ? x : NEG_BIG; e1[4*c+2] = x;
        y = fi1 + fv.w; y = fmaxf(y, ALPHA * y); y = av1[c].w > 0 ? y : NEG_BIG; e1[4*c+3] = y;
        mx1 = fmaxf(fmaxf(x, y), mx1);
    }
    #pragma unroll
    for (int off = 1; off < 64; off <<= 1) {
        mx0 = fmaxf(mx0, __shfl_xor(mx0, off, 64));
        mx1 = fmaxf(mx1, __shfl_xor(mx1, off, 64));
    }
    float s0 = 0.f, s1 = 0.f;
    #pragma unroll
    for (int c = 0; c < 16; c++) {
        e0[c] = __expf(e0[c] - mx0); s0 += e0[c];
        e1[c] = __expf(e1[c] - mx1); s1 += e1[c];
    }
    #pragma unroll
    for (int off = 1; off < 64; off <<= 1) {
        s0 += __shfl_xor(s0, off, 64);
        s1 += __shfl_xor(s1, off, 64);
    }
    const float ri0 = 1.f / s0, ri1 = 1.f / s1;
    const int sw0 = (r0 & 7) << 3, sw1 = (r1 & 7) << 3;
    #pragma unroll
    for (int c = 0; c < 4; c++) {
        const int j = 256 * c + 4 * ln;
        ushort4_t v0 = { f2bf(e0[4*c] * ri0), f2bf(e0[4*c+1] * ri0),
                         f2bf(e0[4*c+2] * ri0), f2bf(e0[4*c+3] * ri0) };
        ushort4_t v1 = { f2bf(e1[4*c] * ri1), f2bf(e1[4*c+1] * ri1),
                         f2bf(e1[4*c+2] * ri1), f2bf(e1[4*c+3] * ri1) };
        *(ushort4_t*)&pbf[r0 * PST + (j ^ sw0)] = v0;
        *(ushort4_t*)&pbf[r1 * PST + (j ^ sw1)] = v1;
    }

    const int n0 = w * 16;
    const unsigned short* hKb = WhK + (size_t)b * 32 * 8192;
    const int arow0 = m * PST, arow1 = (16 + m) * PST;
    const int asw = (m & 7) << 3;
    #define AF0(kt) (*(const short8*)&pbf[arow0 + ((((kt) * 32) + quad * 8) ^ asw)])
    #define AF1(kt) (*(const short8*)&pbf[arow1 + ((((kt) * 32) + quad * 8) ^ asw)])
    #define BF(kt)  (*(const short8*)&hKb[(size_t)(kt) * 8192 + (n0 + m) * 32 + quad * 8])

    short8 bq0 = BF(0), bq1 = BF(1), bq2 = BF(2), bq3 = BF(3);
    __syncthreads();

    f32x4 acc0 = {0.f, 0.f, 0.f, 0.f}, acc1 = acc0;
    short8 a0c = AF0(0), a1c = AF1(0);
    __builtin_amdgcn_s_setprio(1);
    #pragma unroll
    for (int kt = 0; kt < 32; kt++) {
        short8 bnew = bq0, a0n = a0c, a1n = a1c;
        if (kt + 4 < 32) bnew = BF(kt + 4);
        if (kt + 1 < 32) { a0n = AF0(kt + 1); a1n = AF1(kt + 1); }
        acc0 = __builtin_amdgcn_mfma_f32_16x16x32_bf16(a0c, bq0, acc0, 0, 0, 0);
        acc1 = __builtin_amdgcn_mfma_f32_16x16x32_bf16(a1c, bq0, acc1, 0, 0, 0);
        a0c = a0n; a1c = a1n;
        bq0 = bq1; bq1 = bq2; bq2 = bq3; bq3 = bnew;
    }
    __builtin_amdgcn_s_setprio(0);

    const size_t ob = (size_t)(b * Nn) + i0;
    #pragma unroll
    for (int reg = 0; reg < 4; reg++) {
        float v;
        v = acc0[reg]; v = v > 0.f ? v : (__expf(v) - 1.f);
        out[(ob + quad * 4 + reg) * Ff + n0 + m] = v;
        v = acc1[reg]; v = v > 0.f ? v : (__expf(v) - 1.f);
        out[(ob + 16 + quad * 4 + reg) * Ff + n0 + m] = v;
    }
}

extern "C" void kernel_launch(void* const* d_in, const int* in_sizes, int n_in,
                              void* d_out, int out_size, void* d_ws, size_t ws_size,
                              hipStream_t stream)
{
    const void* h   = d_in[0];
    const void* adj = d_in[1];
    const void* W   = d_in[2];
    const void* a   = d_in[3];
    for (int i = 0; i < n_in; i++) {
        if      (in_sizes[i] == Bsz * Nn * Ff) h   = d_in[i];
        else if (in_sizes[i] == Bsz * Nn * Nn) adj = d_in[i];
        else if (in_sizes[i] == Ff * Ff)       W   = d_in[i];
        else if (in_sizes[i] == 2 * Ff)        a   = d_in[i];
    }
    float* out = (float*)d_out;

    char*  wsb = (char*)d_ws;
    float* w1  = (float*)wsb;                                   // 1 KiB
    float* w2  = w1 + Ff;                                       // 1 KiB
    float* f1  = (float*)(wsb + 4096);                          // 64 KiB
    float* f2  = f1 + Bsz * Nn;                                 // 64 KiB
    unsigned short* WhK = (unsigned short*)(wsb + 4096 + 2 * 65536);  // 8 MiB
    unsigned short* WK  = WhK + (size_t)Bsz * 32 * 8192;              // 128 KiB

    const float* hp = (const float*)h;
    const float* Wp = (const float*)W;
    const float* ap = (const float*)a;

    // Try the cooperative merged pre-kernel; on ANY launch error (incl.
    // capture-unsupported) fall back to the proven 2-kernel path. r5 lesson:
    // never leave a cooperative launch unchecked.
    void* args[] = { (void*)&hp, (void*)&Wp, (void*)&ap, (void*)&WK,
                     (void*)&w1, (void*)&w2, (void*)&WhK,
                     (void*)&f1, (void*)&f2 };
    const bool coop_ok =
        hipLaunchCooperativeKernel((void*)k_pre, dim3(512), dim3(256),
                                   args, 0, stream) == hipSuccess;
    if (!coop_ok) {
        gat_prep<<<72, 256, 0, stream>>>(Wp, ap, w1, w2, WK);
        pack_f<<<512, 256, 0, stream>>>(hp, WK, w1, w2, WhK, f1, f2);
    }
    gat_attn<<<Bsz * (Nn / TI), 1024, 0, stream>>>((const int*)adj, f1, f2, WhK, out);
}

// Round 10
// 158.438 us; speedup vs baseline: 1.2951x; 1.2951x over previous
//
#include <hip/hip_runtime.h>
#include <hip/hip_bf16.h>

#define Bsz 16
#define Nn  1024
#define Ff  256
#define ALPHA 0.2f
#define NEG_BIG -9.0e15f

typedef __attribute__((ext_vector_type(8))) short short8;
typedef __attribute__((ext_vector_type(4))) float f32x4;
typedef __attribute__((ext_vector_type(4))) unsigned short ushort4_t;

__device__ __forceinline__ unsigned short f2bf(float x) {
    union { __hip_bfloat16 b; unsigned short u; } cv;
    cv.b = __float2bfloat16(x);
    return cv.u;
}

// ---- K1: fully block-local merge of prep + pack_f -------------------------
// Per block (512 x 256 thr): stage h-tile -> per-K-chunk {stage W chunk to
// LDS wk32 (coalesced) + fold w1/w2 partials from the same registers} ->
// MFMA Wh chunk -> after loop: f1/f2 (fp32, r8 numerics) + WhK pack.
// No cross-block deps: w1/w2 redundant per block but computed from data
// already in registers (zero extra W traffic, unlike r6's column gather).
__global__ __launch_bounds__(256) void k_pack(
    const float* __restrict__ h, const float* __restrict__ W,
    const float* __restrict__ a,
    unsigned short* __restrict__ WhK,
    float* __restrict__ f1, float* __restrict__ f2)
{
    __shared__ __align__(16) float tile[32][258];   // 33,024 B (h tile, f32)
    __shared__ __align__(16) unsigned wk32[4096];   // 16,384 B (W chunk, bf16 pairs)
    __shared__ float w1s[Ff], w2s[Ff];              //  2,048 B
    const int bid = blockIdx.x, t = threadIdx.x, w = t >> 6, ln = t & 63;

    // ---- stage h tile (stride 258: float2 stores, ~2-way transpose reads) --
    const int grow0 = bid * 32;
    const float* src = h + (size_t)grow0 * Ff;
    #pragma unroll
    for (int rr = 0; rr < 8; rr++) {
        const int row = rr * 4 + w;
        const int col = ln * 4;
        const float4 v = *(const float4*)&src[row * Ff + col];
        float2* tr = (float2*)&tile[row][col];
        tr[0] = make_float2(v.x, v.y);
        tr[1] = make_float2(v.z, v.w);
    }

    // thread's chunk-stage coords: row-pair q, o-range og*16..+15
    const int q  = t >> 4;          // 0..15
    const int og = t & 15;          // 0..15
    float4 a1r[4], a2r[4];          // a slices held in registers (no LDS)
    #pragma unroll
    for (int i = 0; i < 4; i++) {
        a1r[i] = *(const float4*)&a[og * 16 + 4 * i];
        a2r[i] = *(const float4*)&a[Ff + og * 16 + 4 * i];
    }
    __syncthreads();

    const int m = ln & 15, quad = ln >> 4;
    f32x4 acc0[4], acc1[4];
    #pragma unroll
    for (int nt = 0; nt < 4; nt++) {
        f32x4 z = {0.f, 0.f, 0.f, 0.f};
        acc0[nt] = z; acc1[nt] = z;
    }
    const unsigned short* wkus = (const unsigned short*)wk32;

    for (int kt = 0; kt < 8; kt++) {
        // ---- stage W chunk kt (rows kt*32..+31): coalesced row reads ----
        const int rowA = kt * 32 + 2 * q;
        const float* wa = W + (size_t)rowA * Ff + og * 16;
        const float* wb = wa + Ff;
        float4 A[4], B[4];
        #pragma unroll
        for (int i = 0; i < 4; i++) {
            A[i] = *(const float4*)&wa[4 * i];
            B[i] = *(const float4*)&wb[4 * i];
        }
        // w1/w2 partials from the same registers
        float s1A = 0.f, s2A = 0.f, s1B = 0.f, s2B = 0.f;
        #pragma unroll
        for (int i = 0; i < 4; i++) {
            s1A += A[i].x * a1r[i].x + A[i].y * a1r[i].y + A[i].z * a1r[i].z + A[i].w * a1r[i].w;
            s2A += A[i].x * a2r[i].x + A[i].y * a2r[i].y + A[i].z * a2r[i].z + A[i].w * a2r[i].w;
            s1B += B[i].x * a1r[i].x + B[i].y * a1r[i].y + B[i].z * a1r[i].z + B[i].w * a1r[i].w;
            s2B += B[i].x * a2r[i].x + B[i].y * a2r[i].y + B[i].z * a2r[i].z + B[i].w * a2r[i].w;
        }
        #pragma unroll
        for (int off = 1; off < 16; off <<= 1) {   // reduce over og (16 lanes)
            s1A += __shfl_xor(s1A, off, 64);
            s2A += __shfl_xor(s2A, off, 64);
            s1B += __shfl_xor(s1B, off, 64);
            s2B += __shfl_xor(s2B, off, 64);
        }
        if (og == 0) {
            w1s[rowA] = s1A; w1s[rowA + 1] = s1B;
            w2s[rowA] = s2A; w2s[rowA + 1] = s2B;
        }
        // pack bf16 pairs: word (o*16 + q) = {lo: W[2q][o], hi: W[2q+1][o]}
        #pragma unroll
        for (int i = 0; i < 4; i++) {
            const int ob = og * 16 + 4 * i;
            wk32[(ob + 0) * 16 + q] = (unsigned)f2bf(A[i].x) | ((unsigned)f2bf(B[i].x) << 16);
            wk32[(ob + 1) * 16 + q] = (unsigned)f2bf(A[i].y) | ((unsigned)f2bf(B[i].y) << 16);
            wk32[(ob + 2) * 16 + q] = (unsigned)f2bf(A[i].z) | ((unsigned)f2bf(B[i].z) << 16);
            wk32[(ob + 3) * 16 + q] = (unsigned)f2bf(A[i].w) | ((unsigned)f2bf(B[i].w) << 16);
        }
        __syncthreads();

        // ---- MFMA chunk: A from h tile (f32->bf16), B from wk32 ----
        short8 a0, a1v;
        {
            const float* p0 = &tile[m][kt * 32 + quad * 8];
            const float* p1 = &tile[16 + m][kt * 32 + quad * 8];
            #pragma unroll
            for (int e = 0; e < 8; e++) {
                a0[e]  = (short)f2bf(p0[e]);
                a1v[e] = (short)f2bf(p1[e]);
            }
        }
        #pragma unroll
        for (int nt = 0; nt < 4; nt++) {
            const short8 bfr = *(const short8*)&wkus[(w * 64 + nt * 16 + m) * 32 + quad * 8];
            acc0[nt] = __builtin_amdgcn_mfma_f32_16x16x32_bf16(a0,  bfr, acc0[nt], 0, 0, 0);
            acc1[nt] = __builtin_amdgcn_mfma_f32_16x16x32_bf16(a1v, bfr, acc1[nt], 0, 0, 0);
        }
        __syncthreads();   // before next chunk overwrites wk32
    }

    // ---- f1/f2 (fp32 h x fp32 w1s — identical numerics to r8) ----
    {
        float w1r[4], w2r[4];
        #pragma unroll
        for (int c = 0; c < 4; c++) {
            w1r[c] = w1s[ln + 64 * c];
            w2r[c] = w2s[ln + 64 * c];
        }
        #pragma unroll
        for (int rr = 0; rr < 2; rr++) {
            const int row = 2 * w + rr;   // wait: 4 waves x 2 = 8 rows only
            (void)row;
        }
        // 4 waves must cover 32 rows: 8 rows per wave
        #pragma unroll
        for (int rr = 0; rr < 8; rr++) {
            const int row = rr * 4 + w;
            float s1 = 0.f, s2 = 0.f;
            #pragma unroll
            for (int c = 0; c < 4; c++) {
                const float hv = tile[row][ln + 64 * c];
                s1 += hv * w1r[c];
                s2 += hv * w2r[c];
            }
            #pragma unroll
            for (int off = 1; off < 64; off <<= 1) {
                s1 += __shfl_xor(s1, off, 64);
                s2 += __shfl_xor(s2, off, 64);
            }
            if (ln == 0) { f1[grow0 + row] = s1; f2[grow0 + row] = s2; }
        }
    }

    // ---- WhK pack (r8 layout: ushort o*32 + node-k) ----
    unsigned short* dst = WhK + (size_t)bid * 8192;
    #pragma unroll
    for (int nt = 0; nt < 4; nt++) {
        const int o = w * 64 + nt * 16 + m;
        ushort4_t v0 = { f2bf(acc0[nt][0]), f2bf(acc0[nt][1]),
                         f2bf(acc0[nt][2]), f2bf(acc0[nt][3]) };
        ushort4_t v1 = { f2bf(acc1[nt][0]), f2bf(acc1[nt][1]),
                         f2bf(acc1[nt][2]), f2bf(acc1[nt][3]) };
        *(ushort4_t*)&dst[o * 32 + quad * 4]      = v0;
        *(ushort4_t*)&dst[o * 32 + 16 + quad * 4] = v1;
    }
}

// ---- K2: softmax -> out = elu( P @ Wh ) (r8-verbatim, 40.9 us proven) -----
#define TI 32
#define PST 1040
__global__ __launch_bounds__(1024, 8) void gat_attn(
    const int* __restrict__ adj,
    const float* __restrict__ f1, const float* __restrict__ f2,
    const unsigned short* __restrict__ WhK,
    float* __restrict__ out)
{
    __shared__ __align__(16) unsigned short pbf[TI * PST];   // 66,560 B
    const int t = threadIdx.x, w = t >> 6, ln = t & 63;      // 16 waves
    const int m = ln & 15, quad = ln >> 4;
    const int bid = blockIdx.x;
    const int b  = 2 * (bid & 7) + ((bid >> 3) & 1);         // XCD-local batches
    const int i0 = (bid >> 4) * TI;

    const int r0 = 2 * w, r1 = r0 + 1;
    const int grb = b * Nn + i0 + r0;
    const int* aptr = adj + (size_t)grb * Nn;
    int4 av0[4], av1[4];
    #pragma unroll
    for (int c = 0; c < 4; c++) {
        av0[c] = *(const int4*)&aptr[c * 256 + 4 * ln];
        av1[c] = *(const int4*)&aptr[Nn + c * 256 + 4 * ln];
    }
    float4 f2r[4];
    #pragma unroll
    for (int c = 0; c < 4; c++)
        f2r[c] = *(const float4*)&f2[b * Nn + 256 * c + 4 * ln];

    const float fi0 = f1[grb], fi1 = f1[grb + 1];
    float e0[16], e1[16];
    float mx0 = -INFINITY, mx1 = -INFINITY;
    #pragma unroll
    for (int c = 0; c < 4; c++) {
        const float4 fv = f2r[c];
        float x, y;
        x = fi0 + fv.x; x = fmaxf(x, ALPHA * x); x = av0[c].x > 0 ? x : NEG_BIG; e0[4*c+0] = x;
        y = fi0 + fv.y; y = fmaxf(y, ALPHA * y); y = av0[c].y > 0 ? y : NEG_BIG; e0[4*c+1] = y;
        mx0 = fmaxf(fmaxf(x, y), mx0);
        x = fi0 + fv.z; x = fmaxf(x, ALPHA * x); x = av0[c].z > 0 ? x : NEG_BIG; e0[4*c+2] = x;
        y = fi0 + fv.w; y = fmaxf(y, ALPHA * y); y = av0[c].w > 0 ? y : NEG_BIG; e0[4*c+3] = y;
        mx0 = fmaxf(fmaxf(x, y), mx0);
        x = fi1 + fv.x; x = fmaxf(x, ALPHA * x); x = av1[c].x > 0 ? x : NEG_BIG; e1[4*c+0] = x;
        y = fi1 + fv.y; y = fmaxf(y, ALPHA * y); y = av1[c].y > 0 ? y : NEG_BIG; e1[4*c+1] = y;
        mx1 = fmaxf(fmaxf(x, y), mx1);
        x = fi1 + fv.z; x = fmaxf(x, ALPHA * x); x = av1[c].z > 0 ? x : NEG_BIG; e1[4*c+2] = x;
        y = fi1 + fv.w; y = fmaxf(y, ALPHA * y); y = av1[c].w > 0 ? y : NEG_BIG; e1[4*c+3] = y;
        mx1 = fmaxf(fmaxf(x, y), mx1);
    }
    #pragma unroll
    for (int off = 1; off < 64; off <<= 1) {
        mx0 = fmaxf(mx0, __shfl_xor(mx0, off, 64));
        mx1 = fmaxf(mx1, __shfl_xor(mx1, off, 64));
    }
    float s0 = 0.f, s1 = 0.f;
    #pragma unroll
    for (int c = 0; c < 16; c++) {
        e0[c] = __expf(e0[c] - mx0); s0 += e0[c];
        e1[c] = __expf(e1[c] - mx1); s1 += e1[c];
    }
    #pragma unroll
    for (int off = 1; off < 64; off <<= 1) {
        s0 += __shfl_xor(s0, off, 64);
        s1 += __shfl_xor(s1, off, 64);
    }
    const float ri0 = 1.f / s0, ri1 = 1.f / s1;
    const int sw0 = (r0 & 7) << 3, sw1 = (r1 & 7) << 3;
    #pragma unroll
    for (int c = 0; c < 4; c++) {
        const int j = 256 * c + 4 * ln;
        ushort4_t v0 = { f2bf(e0[4*c] * ri0), f2bf(e0[4*c+1] * ri0),
                         f2bf(e0[4*c+2] * ri0), f2bf(e0[4*c+3] * ri0) };
        ushort4_t v1 = { f2bf(e1[4*c] * ri1), f2bf(e1[4*c+1] * ri1),
                         f2bf(e1[4*c+2] * ri1), f2bf(e1[4*c+3] * ri1) };
        *(ushort4_t*)&pbf[r0 * PST + (j ^ sw0)] = v0;
        *(ushort4_t*)&pbf[r1 * PST + (j ^ sw1)] = v1;
    }

    const int n0 = w * 16;
    const unsigned short* hKb = WhK + (size_t)b * 32 * 8192;
    const int arow0 = m * PST, arow1 = (16 + m) * PST;
    const int asw = (m & 7) << 3;
    #define AF0(kt) (*(const short8*)&pbf[arow0 + ((((kt) * 32) + quad * 8) ^ asw)])
    #define AF1(kt) (*(const short8*)&pbf[arow1 + ((((kt) * 32) + quad * 8) ^ asw)])
    #define BF(kt)  (*(const short8*)&hKb[(size_t)(kt) * 8192 + (n0 + m) * 32 + quad * 8])

    short8 bq0 = BF(0), bq1 = BF(1), bq2 = BF(2), bq3 = BF(3);
    __syncthreads();

    f32x4 acc0 = {0.f, 0.f, 0.f, 0.f}, acc1 = acc0;
    short8 a0c = AF0(0), a1c = AF1(0);
    __builtin_amdgcn_s_setprio(1);
    #pragma unroll
    for (int kt = 0; kt < 32; kt++) {
        short8 bnew = bq0, a0n = a0c, a1n = a1c;
        if (kt + 4 < 32) bnew = BF(kt + 4);
        if (kt + 1 < 32) { a0n = AF0(kt + 1); a1n = AF1(kt + 1); }
        acc0 = __builtin_amdgcn_mfma_f32_16x16x32_bf16(a0c, bq0, acc0, 0, 0, 0);
        acc1 = __builtin_amdgcn_mfma_f32_16x16x32_bf16(a1c, bq0, acc1, 0, 0, 0);
        a0c = a0n; a1c = a1n;
        bq0 = bq1; bq1 = bq2; bq2 = bq3; bq3 = bnew;
    }
    __builtin_amdgcn_s_setprio(0);

    const size_t ob = (size_t)(b * Nn) + i0;
    #pragma unroll
    for (int reg = 0; reg < 4; reg++) {
        float v;
        v = acc0[reg]; v = v > 0.f ? v : (__expf(v) - 1.f);
        out[(ob + quad * 4 + reg) * Ff + n0 + m] = v;
        v = acc1[reg]; v = v > 0.f ? v : (__expf(v) - 1.f);
        out[(ob + 16 + quad * 4 + reg) * Ff + n0 + m] = v;
    }
}

extern "C" void kernel_launch(void* const* d_in, const int* in_sizes, int n_in,
                              void* d_out, int out_size, void* d_ws, size_t ws_size,
                              hipStream_t stream)
{
    const void* h   = d_in[0];
    const void* adj = d_in[1];
    const void* W   = d_in[2];
    const void* a   = d_in[3];
    for (int i = 0; i < n_in; i++) {
        if      (in_sizes[i] == Bsz * Nn * Ff) h   = d_in[i];
        else if (in_sizes[i] == Bsz * Nn * Nn) adj = d_in[i];
        else if (in_sizes[i] == Ff * Ff)       W   = d_in[i];
        else if (in_sizes[i] == 2 * Ff)        a   = d_in[i];
    }
    char* wsb = (char*)d_ws;
    float* f1 = (float*)wsb;                                  // 64 KiB
    float* f2 = (float*)(wsb + 65536);                        // 64 KiB
    unsigned short* WhK = (unsigned short*)(wsb + 131072);    // 8 MiB

    k_pack<<<512, 256, 0, stream>>>((const float*)h, (const float*)W,
                                    (const float*)a, WhK, f1, f2);
    gat_attn<<<Bsz * (Nn / TI), 1024, 0, stream>>>((const int*)adj, f1, f2,
                                                   WhK, (float*)d_out);
}